// Round 1
// baseline (365.094 us; speedup 1.0000x reference)
//
#include <hip/hip_runtime.h>
#include <math.h>

#define NQ     2048
#define DMODEL 512
#define NH     8
#define DHD    64
#define MEMT   512
#define KVT    2560
#define QSCALE 0.125f
#define NEGF   (-1e30f)

// ---------------------------------------------------------------------------
// Generic 64x64-tile f32 GEMM: C[M,Ncols] = A[M,K] @ B[K,Ncols]
// MODE 0: write to q_ws laid out [H][NQ][DH]
// MODE 1: cols 0..511 -> k_all rows MEM+r, cols 512..1023 -> v_all rows MEM+r
//         (layout [H][KVT][DH])
// MODE 2: plain row-major [M][Ncols] (final output)
// ---------------------------------------------------------------------------
template<int MODE>
__global__ __launch_bounds__(256) void gemm_tiled(const float* __restrict__ A,
                                                  const float* __restrict__ B,
                                                  float* __restrict__ out0,
                                                  float* __restrict__ out1,
                                                  int M, int K, int Ncols) {
    __shared__ float As[16][64];
    __shared__ float Bs[16][64];
    int tid = threadIdx.x;
    int tx = tid & 15, ty = tid >> 4;
    int bx = blockIdx.x, by = blockIdx.y;

    float acc[4][4];
#pragma unroll
    for (int i = 0; i < 4; ++i)
#pragma unroll
        for (int j = 0; j < 4; ++j) acc[i][j] = 0.f;

    int arow  = by * 64 + (tid >> 2);
    int aquad = (tid & 3) * 4;
    int bkk   = tid >> 4;
    int bj    = (tid & 15) * 4;

    for (int k0 = 0; k0 < K; k0 += 16) {
        float4 a4 = *(const float4*)&A[arow * K + k0 + aquad];
        As[aquad + 0][tid >> 2] = a4.x;
        As[aquad + 1][tid >> 2] = a4.y;
        As[aquad + 2][tid >> 2] = a4.z;
        As[aquad + 3][tid >> 2] = a4.w;
        *(float4*)&Bs[bkk][bj] = *(const float4*)&B[(k0 + bkk) * Ncols + bx * 64 + bj];
        __syncthreads();
#pragma unroll
        for (int kk = 0; kk < 16; ++kk) {
            float4 av = *(float4*)&As[kk][ty * 4];
            float4 bv = *(float4*)&Bs[kk][tx * 4];
            float ar[4] = {av.x, av.y, av.z, av.w};
            float br[4] = {bv.x, bv.y, bv.z, bv.w};
#pragma unroll
            for (int i = 0; i < 4; ++i)
#pragma unroll
                for (int j = 0; j < 4; ++j) acc[i][j] += ar[i] * br[j];
        }
        __syncthreads();
    }

#pragma unroll
    for (int i = 0; i < 4; ++i) {
        int r = by * 64 + ty * 4 + i;
#pragma unroll
        for (int j = 0; j < 4; ++j) {
            int c = bx * 64 + tx * 4 + j;
            float val = acc[i][j];
            if (MODE == 0) {
                int h = c >> 6, d = c & 63;
                out0[(h * NQ + r) * DHD + d] = val;
            } else if (MODE == 1) {
                if (c < 512) {
                    int h = c >> 6, d = c & 63;
                    out0[(h * KVT + MEMT + r) * DHD + d] = val;
                } else {
                    int c2 = c - 512;
                    int h = c2 >> 6, d = c2 & 63;
                    out1[(h * KVT + MEMT + r) * DHD + d] = val;
                }
            } else {
                out0[r * DMODEL + c] = val;
            }
        }
    }
}

// ---------------------------------------------------------------------------
// Gates: sigmoid(x @ Wg) -> gates[h][n]
// ---------------------------------------------------------------------------
__global__ __launch_bounds__(256) void gates_kernel(const float* __restrict__ x,
                                                    const float* __restrict__ Wg,
                                                    float* __restrict__ gates) {
    int t = blockIdx.x * 256 + threadIdx.x;   // 16384 threads
    int n = t >> 3, h = t & 7;
    float acc = 0.f;
    for (int k = 0; k < DMODEL; ++k) acc += x[n * DMODEL + k] * Wg[k * NH + h];
    gates[h * NQ + n] = 1.f / (1.f + expf(-acc));
}

// ---------------------------------------------------------------------------
// RoPE on q in place. q layout [H][NQ][DH], position = 512 + n.
// ---------------------------------------------------------------------------
__global__ __launch_bounds__(256) void rope_q_kernel(float* __restrict__ q) {
    int t = blockIdx.x * 256 + threadIdx.x;   // H*NQ*32 = 524288
    int j = t & 31;
    int n = (t >> 5) & 2047;
    int h = t >> 16;
    int base = (h * NQ + n) * DHD;
    float a = q[base + j], b = q[base + 32 + j];
    float pos = (float)(512 + n);
    float inv = powf(10000.f, -(float)j * (1.f / 32.f));
    float f = pos * inv;
    float c = cosf(f), s = sinf(f);
    q[base + j]      = a * c - b * s;
    q[base + 32 + j] = b * c + a * s;
}

// ---------------------------------------------------------------------------
// RoPE on k (all KVT rows; rows < MEM sourced from cache_k, rows >= MEM in
// place in k_all) + copy cache_v into v_all rows < MEM. pos = row index.
// ---------------------------------------------------------------------------
__global__ __launch_bounds__(256) void rope_k_copy_kernel(const float* __restrict__ cache_k,
                                                          const float* __restrict__ cache_v,
                                                          float* __restrict__ k_all,
                                                          float* __restrict__ v_all) {
    int t = blockIdx.x * 256 + threadIdx.x;   // H*KVT*32 = 655360
    int j = t & 31;
    int r = (t >> 5) % KVT;
    int h = t / (KVT * 32);
    int dst = (h * KVT + r) * DHD;
    float a, b;
    if (r < MEMT) {
        int src = (h * MEMT + r) * DHD;
        a = cache_k[src + j];
        b = cache_k[src + 32 + j];
        v_all[dst + j]      = cache_v[src + j];
        v_all[dst + 32 + j] = cache_v[src + 32 + j];
    } else {
        a = k_all[dst + j];
        b = k_all[dst + 32 + j];
    }
    float inv = powf(10000.f, -(float)j * (1.f / 32.f));
    float f = (float)r * inv;
    float c = cosf(f), s = sinf(f);
    k_all[dst + j]      = a * c - b * s;
    k_all[dst + 32 + j] = b * c + a * s;
}

// ---------------------------------------------------------------------------
// Flash attention with the XL mask. One block = (head, 64 queries).
// Valid keys per query q_pos=512+qrow: [ (q_pos/512 - 1)*512 , q_pos ] AND
// episode_ids[k_pos]==episode_ids[q_pos].
// Thread (qi,dg): qi = query in block, dg = 16-wide slice of DH / key slice.
// ---------------------------------------------------------------------------
__global__ __launch_bounds__(256) void attn_kernel(const float* __restrict__ q,
                                                   const float* __restrict__ k,
                                                   const float* __restrict__ v,
                                                   const float* __restrict__ gates,
                                                   const int* __restrict__ ep,
                                                   float* __restrict__ out) {
    __shared__ float Ks[64][64];
    __shared__ float Vs[64][64];
    __shared__ float Sc[64][65];   // pad: avoid 16-way bank conflict on column reads

    int h   = blockIdx.y;
    int q0  = blockIdx.x * 64;
    int tid = threadIdx.x;
    int qi  = tid >> 2, dg = tid & 3;
    int qrow = q0 + qi;
    int qpos = 512 + qrow;
    int epq  = ep[qpos];

    // q row into registers
    float qreg[64];
    const float4* qp = (const float4*)&q[(h * NQ + qrow) * DHD];
#pragma unroll
    for (int j4 = 0; j4 < 16; ++j4) {
        float4 t4 = qp[j4];
        qreg[4 * j4 + 0] = t4.x; qreg[4 * j4 + 1] = t4.y;
        qreg[4 * j4 + 2] = t4.z; qreg[4 * j4 + 3] = t4.w;
    }

    float m = NEGF, l = 0.f;
    float o[16];
#pragma unroll
    for (int dd = 0; dd < 16; ++dd) o[dd] = 0.f;

    int c_lo  = q0 & ~511;          // (bq-1)*WINDOW
    int c_end = 512 + q0 + 64;      // exclusive

    for (int c0 = c_lo; c0 < c_end; c0 += 64) {
        // stage K/V chunk
#pragma unroll
        for (int u = 0; u < 4; ++u) {
            int l4 = tid + u * 256;              // 1024 float4s
            int row = l4 >> 4, col4 = (l4 & 15) * 4;
            *(float4*)&Ks[row][col4] = *(const float4*)&k[(h * KVT + c0 + row) * DHD + col4];
            *(float4*)&Vs[row][col4] = *(const float4*)&v[(h * KVT + c0 + row) * DHD + col4];
        }
        __syncthreads();

        // scores for this thread's 16 keys
#pragma unroll
        for (int tt = 0; tt < 16; ++tt) {
            int t = dg * 16 + tt;
            int kpos = c0 + t;
            float s = NEGF;
            if (kpos <= qpos && ep[kpos] == epq) {
                float acc = 0.f;
#pragma unroll
                for (int kk = 0; kk < 64; ++kk) acc += qreg[kk] * Ks[t][kk];
                s = acc * QSCALE;
            }
            Sc[qi][t] = s;
        }
        __syncthreads();

        // online softmax + PV (all 4 dg threads of a query redo the stats)
        float cmax = NEGF;
        for (int t = 0; t < 64; ++t) cmax = fmaxf(cmax, Sc[qi][t]);
        float mn = fmaxf(m, cmax);
        if (mn > -1e29f) {
            float r = expf(m - mn);
            l *= r;
#pragma unroll
            for (int dd = 0; dd < 16; ++dd) o[dd] *= r;
            for (int t = 0; t < 64; ++t) {
                float p = expf(Sc[qi][t] - mn);
                l += p;
#pragma unroll
                for (int dd = 0; dd < 16; ++dd) o[dd] += p * Vs[t][dg * 16 + dd];
            }
            m = mn;
        }
        __syncthreads();
    }

    float g = gates[h * NQ + qrow];
    float s = g / l;
#pragma unroll
    for (int dd = 0; dd < 16; ++dd)
        out[qrow * DMODEL + h * DHD + dg * 16 + dd] = o[dd] * s;
}

// ---------------------------------------------------------------------------
extern "C" void kernel_launch(void* const* d_in, const int* in_sizes, int n_in,
                              void* d_out, int out_size, void* d_ws, size_t ws_size,
                              hipStream_t stream) {
    const float* x       = (const float*)d_in[0];
    const float* cache_k = (const float*)d_in[1];
    const float* cache_v = (const float*)d_in[2];
    const int*   ep      = (const int*)  d_in[3];
    const float* Wq      = (const float*)d_in[4];
    const float* Wkv     = (const float*)d_in[5];
    const float* Wg      = (const float*)d_in[6];
    const float* Wo      = (const float*)d_in[7];
    float* out = (float*)d_out;

    float* ws       = (float*)d_ws;
    float* q_ws     = ws;                       // [8][2048][64]  = 1048576
    float* k_all    = q_ws + 1048576;           // [8][2560][64]  = 1310720
    float* v_all    = k_all + 1310720;          // [8][2560][64]  = 1310720
    float* gatesw   = v_all + 1310720;          // [8][2048]      = 16384
    float* attn_out = gatesw + 16384;           // [2048][512]    = 1048576
                                                // total 18.9 MB of ws

    gemm_tiled<0><<<dim3(8, 32),  256, 0, stream>>>(x, Wq,  q_ws,  nullptr, NQ, DMODEL, 512);
    gemm_tiled<1><<<dim3(16, 32), 256, 0, stream>>>(x, Wkv, k_all, v_all,   NQ, DMODEL, 1024);
    gates_kernel<<<64, 256, 0, stream>>>(x, Wg, gatesw);
    rope_q_kernel<<<2048, 256, 0, stream>>>(q_ws);
    rope_k_copy_kernel<<<2560, 256, 0, stream>>>(cache_k, cache_v, k_all, v_all);
    attn_kernel<<<dim3(32, 8), 256, 0, stream>>>(q_ws, k_all, v_all, gatesw, ep, attn_out);
    gemm_tiled<2><<<dim3(8, 32), 256, 0, stream>>>(attn_out, Wo, out, nullptr, NQ, DMODEL, 512);
}

// Round 2
// 226.953 us; speedup vs baseline: 1.6087x; 1.6087x over previous
//
#include <hip/hip_runtime.h>
#include <math.h>

#define NQ     2048
#define DMODEL 512
#define NH     8
#define DHD    64
#define MEMT   512
#define KVT    2560
#define QSCALE 0.125f
#define NEGF   (-1e30f)

typedef unsigned short u16;
typedef __bf16 bf16x8 __attribute__((ext_vector_type(8)));
typedef float  f32x4  __attribute__((ext_vector_type(4)));
typedef u16    u16x8  __attribute__((ext_vector_type(8)));
typedef u16    u16x4  __attribute__((ext_vector_type(4)));

__device__ __forceinline__ u16 f2bf(float f) {
    union { float f; unsigned u; } v; v.f = f;
    unsigned r = (v.u + 0x7FFFu + ((v.u >> 16) & 1u)) >> 16;
    return (u16)r;
}

// ---------------------------------------------------------------------------
// Generic 64x64-tile f32 GEMM: C[M,Ncols] = A[M,K] @ B[K,Ncols]
// MODE 0: write q_f32 laid out [H][NQ][DH]
// MODE 1: cols 0..511 -> kn [H][NQ][DH], cols 512..1023 -> vn [H][NQ][DH]
// MODE 2: plain row-major (final output)
// ---------------------------------------------------------------------------
template<int MODE>
__global__ __launch_bounds__(256) void gemm_tiled(const float* __restrict__ A,
                                                  const float* __restrict__ B,
                                                  float* __restrict__ out0,
                                                  float* __restrict__ out1,
                                                  int M, int K, int Ncols) {
    __shared__ float As[16][64];
    __shared__ float Bs[16][64];
    int tid = threadIdx.x;
    int tx = tid & 15, ty = tid >> 4;
    int bx = blockIdx.x, by = blockIdx.y;

    float acc[4][4];
#pragma unroll
    for (int i = 0; i < 4; ++i)
#pragma unroll
        for (int j = 0; j < 4; ++j) acc[i][j] = 0.f;

    int arow  = by * 64 + (tid >> 2);
    int aquad = (tid & 3) * 4;
    int bkk   = tid >> 4;
    int bj    = (tid & 15) * 4;

    for (int k0 = 0; k0 < K; k0 += 16) {
        float4 a4 = *(const float4*)&A[arow * K + k0 + aquad];
        As[aquad + 0][tid >> 2] = a4.x;
        As[aquad + 1][tid >> 2] = a4.y;
        As[aquad + 2][tid >> 2] = a4.z;
        As[aquad + 3][tid >> 2] = a4.w;
        *(float4*)&Bs[bkk][bj] = *(const float4*)&B[(k0 + bkk) * Ncols + bx * 64 + bj];
        __syncthreads();
#pragma unroll
        for (int kk = 0; kk < 16; ++kk) {
            float4 av = *(float4*)&As[kk][ty * 4];
            float4 bv = *(float4*)&Bs[kk][tx * 4];
            float ar[4] = {av.x, av.y, av.z, av.w};
            float br[4] = {bv.x, bv.y, bv.z, bv.w};
#pragma unroll
            for (int i = 0; i < 4; ++i)
#pragma unroll
                for (int j = 0; j < 4; ++j) acc[i][j] += ar[i] * br[j];
        }
        __syncthreads();
    }

#pragma unroll
    for (int i = 0; i < 4; ++i) {
        int r = by * 64 + ty * 4 + i;
#pragma unroll
        for (int j = 0; j < 4; ++j) {
            int c = bx * 64 + tx * 4 + j;
            float val = acc[i][j];
            if (MODE == 0) {
                int h = c >> 6, d = c & 63;
                out0[(h * NQ + r) * DHD + d] = val;
            } else if (MODE == 1) {
                if (c < 512) {
                    int h = c >> 6, d = c & 63;
                    out0[(h * NQ + r) * DHD + d] = val;
                } else {
                    int c2 = c - 512;
                    int h = c2 >> 6, d = c2 & 63;
                    out1[(h * NQ + r) * DHD + d] = val;
                }
            } else {
                out0[r * DMODEL + c] = val;
            }
        }
    }
}

// ---------------------------------------------------------------------------
__global__ __launch_bounds__(256) void gates_kernel(const float* __restrict__ x,
                                                    const float* __restrict__ Wg,
                                                    float* __restrict__ gates) {
    int t = blockIdx.x * 256 + threadIdx.x;
    int n = t >> 3, h = t & 7;
    float acc = 0.f;
    for (int k = 0; k < DMODEL; ++k) acc += x[n * DMODEL + k] * Wg[k * NH + h];
    gates[h * NQ + n] = 1.f / (1.f + expf(-acc));
}

// ---------------------------------------------------------------------------
// RoPE on q: read q_f32 [H][NQ][DH], write bf16 q_bf. pos = 512 + n.
// ---------------------------------------------------------------------------
__global__ __launch_bounds__(256) void rope_q_bf(const float* __restrict__ q,
                                                 u16* __restrict__ qb) {
    int t = blockIdx.x * 256 + threadIdx.x;   // 524288
    int j = t & 31;
    int n = (t >> 5) & 2047;
    int h = t >> 16;
    int base = (h * NQ + n) * DHD;
    float a = q[base + j], b = q[base + 32 + j];
    float pos = (float)(512 + n);
    float inv = powf(10000.f, -(float)j * (1.f / 32.f));
    float f = pos * inv;
    float c = cosf(f), s = sinf(f);
    qb[base + j]      = f2bf(a * c - b * s);
    qb[base + 32 + j] = f2bf(b * c + a * s);
}

// ---------------------------------------------------------------------------
// RoPE on k: rows<MEM from cache_k, rows>=MEM from kn ([H][NQ][DH]).
// Write bf16 k_bf [H][KVT][DH]. pos = row.
// ---------------------------------------------------------------------------
__global__ __launch_bounds__(256) void rope_k_bf(const float* __restrict__ cache_k,
                                                 const float* __restrict__ kn,
                                                 u16* __restrict__ kb) {
    int t = blockIdx.x * 256 + threadIdx.x;   // 655360
    int j = t & 31;
    int r = (t >> 5) % KVT;
    int h = t / (KVT * 32);
    float a, b;
    if (r < MEMT) {
        int src = (h * MEMT + r) * DHD;
        a = cache_k[src + j];
        b = cache_k[src + 32 + j];
    } else {
        int src = (h * NQ + (r - MEMT)) * DHD;
        a = kn[src + j];
        b = kn[src + 32 + j];
    }
    float inv = powf(10000.f, -(float)j * (1.f / 32.f));
    float f = (float)r * inv;
    float c = cosf(f), s = sinf(f);
    int dst = (h * KVT + r) * DHD;
    kb[dst + j]      = f2bf(a * c - b * s);
    kb[dst + 32 + j] = f2bf(b * c + a * s);
}

// ---------------------------------------------------------------------------
// V transpose + bf16: rows<MEM from cache_v, else vn -> vT [H][DH][KVT]
// ---------------------------------------------------------------------------
__global__ __launch_bounds__(256) void transpose_v(const float* __restrict__ cache_v,
                                                   const float* __restrict__ vn,
                                                   u16* __restrict__ vt) {
    __shared__ float tile[64][65];
    int h = blockIdx.y;
    int c0 = blockIdx.x * 64;
    int tid = threadIdx.x;
    int rr = tid >> 4, cc = (tid & 15) * 4;
#pragma unroll
    for (int u = 0; u < 4; ++u) {
        int row = u * 16 + rr;
        int r = c0 + row;
        float4 val;
        if (r < MEMT) val = *(const float4*)&cache_v[(h * MEMT + r) * DHD + cc];
        else          val = *(const float4*)&vn[(h * NQ + (r - MEMT)) * DHD + cc];
        tile[row][cc + 0] = val.x; tile[row][cc + 1] = val.y;
        tile[row][cc + 2] = val.z; tile[row][cc + 3] = val.w;
    }
    __syncthreads();
#pragma unroll
    for (int u = 0; u < 4; ++u) {
        int d = u * 16 + rr;
        u16x4 o;
#pragma unroll
        for (int i = 0; i < 4; ++i) o[i] = f2bf(tile[cc + i][d]);
        *(u16x4*)&vt[(h * DHD + d) * KVT + c0 + cc] = o;
    }
}

// ---------------------------------------------------------------------------
// MFMA flash attention. Block = (64-query chunk, head), 4 waves, wave = 16 q.
// ---------------------------------------------------------------------------
#define LOADK(BK, BEP, C0)                                                     \
  _Pragma("unroll")                                                            \
  for (int t = 0; t < 4; ++t) {                                                \
    const u16* kr = kb + ((h * KVT + (C0) + t * 16 + lr) * DHD + lg * 8);      \
    BK[t][0] = __builtin_bit_cast(bf16x8, *(const u16x8*)kr);                  \
    BK[t][1] = __builtin_bit_cast(bf16x8, *(const u16x8*)(kr + 32));           \
    BEP[t] = ep[(C0) + t * 16 + lr];                                           \
  }

#define DO_CHUNK(C0, BK, BEP, PREF, NBK, NBEP)                                 \
  {                                                                            \
    bf16x8 bV[4][2];                                                           \
    _Pragma("unroll")                                                          \
    for (int t = 0; t < 4; ++t) {                                              \
      const u16* vr = vtb + ((h * DHD + t * 16 + lr) * KVT + (C0) + lg * 8);   \
      bV[t][0] = __builtin_bit_cast(bf16x8, *(const u16x8*)vr);                \
      bV[t][1] = __builtin_bit_cast(bf16x8, *(const u16x8*)(vr + 32));         \
    }                                                                          \
    f32x4 s[4];                                                                \
    _Pragma("unroll")                                                          \
    for (int t = 0; t < 4; ++t) {                                              \
      f32x4 z = {0.f, 0.f, 0.f, 0.f};                                          \
      s[t] = __builtin_amdgcn_mfma_f32_16x16x32_bf16(aQ[0], BK[t][0], z, 0, 0, 0); \
      s[t] = __builtin_amdgcn_mfma_f32_16x16x32_bf16(aQ[1], BK[t][1], s[t], 0, 0, 0); \
    }                                                                          \
    if (PREF) { LOADK(NBK, NBEP, (C0) + 64) }                                  \
    float rmax[4] = {NEGF, NEGF, NEGF, NEGF};                                  \
    _Pragma("unroll")                                                          \
    for (int t = 0; t < 4; ++t) {                                              \
      int key = (C0) + t * 16 + lr;                                            \
      int ek = BEP[t];                                                         \
      _Pragma("unroll")                                                        \
      for (int r = 0; r < 4; ++r) {                                            \
        bool vld = (key <= qpos[r]) && (ek == epq[r]);                         \
        float sv = vld ? s[t][r] * QSCALE : NEGF;                              \
        s[t][r] = sv;                                                          \
        rmax[r] = fmaxf(rmax[r], sv);                                          \
      }                                                                        \
    }                                                                          \
    _Pragma("unroll")                                                          \
    for (int mm = 1; mm < 16; mm <<= 1) {                                      \
      _Pragma("unroll")                                                        \
      for (int r = 0; r < 4; ++r)                                              \
        rmax[r] = fmaxf(rmax[r], __shfl_xor(rmax[r], mm, 64));                 \
    }                                                                          \
    float alpha[4];                                                            \
    _Pragma("unroll")                                                          \
    for (int r = 0; r < 4; ++r) {                                              \
      float mn = fmaxf(mrun[r], rmax[r]);                                      \
      alpha[r] = __expf(mrun[r] - mn);                                         \
      mrun[r] = mn;                                                            \
      lsum[r] *= alpha[r];                                                     \
    }                                                                          \
    _Pragma("unroll")                                                          \
    for (int t = 0; t < 4; ++t)                                                \
      _Pragma("unroll")                                                        \
      for (int r = 0; r < 4; ++r) o[t][r] *= alpha[r];                         \
    float psum[4] = {0.f, 0.f, 0.f, 0.f};                                      \
    _Pragma("unroll")                                                          \
    for (int t = 0; t < 4; ++t) {                                              \
      _Pragma("unroll")                                                        \
      for (int r = 0; r < 4; ++r) {                                            \
        float sv = s[t][r];                                                    \
        float p = (sv <= -1e29f) ? 0.f : __expf(sv - mrun[r]);                 \
        psum[r] += p;                                                          \
        int qq = lg * 4 + r;                                                   \
        int kk2 = t * 16 + lr;                                                 \
        pl[qq * 64 + (kk2 ^ ((qq & 7) << 3))] = f2bf(p);                       \
      }                                                                        \
    }                                                                          \
    _Pragma("unroll")                                                          \
    for (int mm = 1; mm < 16; mm <<= 1) {                                      \
      _Pragma("unroll")                                                        \
      for (int r = 0; r < 4; ++r) psum[r] += __shfl_xor(psum[r], mm, 64);      \
    }                                                                          \
    _Pragma("unroll")                                                          \
    for (int r = 0; r < 4; ++r) lsum[r] += psum[r];                            \
    bf16x8 aP[2];                                                              \
    {                                                                          \
      int sw = (lr & 7) << 3;                                                  \
      aP[0] = __builtin_bit_cast(bf16x8, *(const u16x8*)&pl[lr * 64 + ((lg * 8) ^ sw)]);        \
      aP[1] = __builtin_bit_cast(bf16x8, *(const u16x8*)&pl[lr * 64 + ((32 + lg * 8) ^ sw)]);   \
    }                                                                          \
    _Pragma("unroll")                                                          \
    for (int t = 0; t < 4; ++t) {                                              \
      o[t] = __builtin_amdgcn_mfma_f32_16x16x32_bf16(aP[0], bV[t][0], o[t], 0, 0, 0); \
      o[t] = __builtin_amdgcn_mfma_f32_16x16x32_bf16(aP[1], bV[t][1], o[t], 0, 0, 0); \
    }                                                                          \
  }

__global__ __launch_bounds__(256, 1) void attn_mfma(const u16* __restrict__ qb,
                                                    const u16* __restrict__ kb,
                                                    const u16* __restrict__ vtb,
                                                    const float* __restrict__ gates,
                                                    const int* __restrict__ ep,
                                                    float* __restrict__ outp) {
    __shared__ u16 plds[4][16 * 64];
    int h = blockIdx.y;
    int q0 = blockIdx.x * 64;
    int tid = threadIdx.x;
    int w = tid >> 6, lane = tid & 63;
    int lr = lane & 15, lg = lane >> 4;
    int qbase = q0 + w * 16;
    u16* pl = plds[w];

    bf16x8 aQ[2];
    {
        const u16* qrow = qb + ((h * NQ + qbase + lr) * DHD + lg * 8);
        aQ[0] = __builtin_bit_cast(bf16x8, *(const u16x8*)qrow);
        aQ[1] = __builtin_bit_cast(bf16x8, *(const u16x8*)(qrow + 32));
    }

    int qpos[4], epq[4];
    float gq[4];
#pragma unroll
    for (int r = 0; r < 4; ++r) {
        int q = qbase + lg * 4 + r;
        qpos[r] = 512 + q;
        epq[r] = ep[512 + q];
        gq[r] = gates[h * NQ + q];
    }

    f32x4 o[4];
    float mrun[4], lsum[4];
#pragma unroll
    for (int t = 0; t < 4; ++t) { f32x4 z = {0.f,0.f,0.f,0.f}; o[t] = z; }
#pragma unroll
    for (int r = 0; r < 4; ++r) { mrun[r] = NEGF; lsum[r] = 0.f; }

    int c_lo = q0 & ~511;
    int nch = 9 + ((q0 >> 6) & 7);

    bf16x8 bKA[4][2], bKB[4][2];
    int epA[4], epB[4];

    LOADK(bKA, epA, c_lo)
    int c0 = c_lo, ci = 0;
    while (true) {
        bool more = (ci + 1 < nch);
        DO_CHUNK(c0, bKA, epA, more, bKB, epB)
        ++ci; c0 += 64;
        if (!more) break;
        bool more2 = (ci + 1 < nch);
        DO_CHUNK(c0, bKB, epB, more2, bKA, epA)
        ++ci; c0 += 64;
        if (!more2) break;
    }

#pragma unroll
    for (int r = 0; r < 4; ++r) {
        float inv = gq[r] / lsum[r];
        int q = qbase + lg * 4 + r;
#pragma unroll
        for (int t = 0; t < 4; ++t)
            outp[q * DMODEL + h * DHD + t * 16 + lr] = o[t][r] * inv;
    }
}

// ---------------------------------------------------------------------------
extern "C" void kernel_launch(void* const* d_in, const int* in_sizes, int n_in,
                              void* d_out, int out_size, void* d_ws, size_t ws_size,
                              hipStream_t stream) {
    const float* x       = (const float*)d_in[0];
    const float* cache_k = (const float*)d_in[1];
    const float* cache_v = (const float*)d_in[2];
    const int*   ep      = (const int*)  d_in[3];
    const float* Wq      = (const float*)d_in[4];
    const float* Wkv     = (const float*)d_in[5];
    const float* Wg      = (const float*)d_in[6];
    const float* Wo      = (const float*)d_in[7];
    float* out = (float*)d_out;

    float* ws     = (float*)d_ws;
    float* q_f32  = ws;                         // 1048576 f  (later reused as attn_out)
    float* kn     = ws + 1048576;               // 1048576 f
    float* vn     = ws + 2097152;               // 1048576 f
    float* gatesw = ws + 3145728;               // 16384 f
    u16*   q_bf   = (u16*)(ws + 3162112);       // 1048576 u16
    u16*   k_bf   = q_bf + 1048576;             // 1310720 u16
    u16*   vT_bf  = k_bf + 1310720;             // 1310720 u16
    float* attn_out = q_f32;                    // alias: q_f32 dead after rope_q_bf

    gemm_tiled<0><<<dim3(8, 32),  256, 0, stream>>>(x, Wq,  q_f32, nullptr, NQ, DMODEL, 512);
    gemm_tiled<1><<<dim3(16, 32), 256, 0, stream>>>(x, Wkv, kn,    vn,      NQ, DMODEL, 1024);
    gates_kernel<<<64, 256, 0, stream>>>(x, Wg, gatesw);
    rope_q_bf<<<2048, 256, 0, stream>>>(q_f32, q_bf);
    rope_k_bf<<<2560, 256, 0, stream>>>(cache_k, kn, k_bf);
    transpose_v<<<dim3(40, 8), 256, 0, stream>>>(cache_v, vn, vT_bf);
    attn_mfma<<<dim3(32, 8), 256, 0, stream>>>(q_bf, k_bf, vT_bf, gatesw, ep, attn_out);
    gemm_tiled<2><<<dim3(8, 32), 256, 0, stream>>>(attn_out, Wo, out, nullptr, NQ, DMODEL, 512);
}

// Round 3
// 158.545 us; speedup vs baseline: 2.3028x; 1.4315x over previous
//
#include <hip/hip_runtime.h>
#include <math.h>

#define NQ     2048
#define DMODEL 512
#define NH     8
#define DHD    64
#define MEMT   512
#define KVT    2560
#define QSCALE 0.125f
#define NEGF   (-1e30f)

typedef unsigned short u16;
typedef __bf16 bf16x8 __attribute__((ext_vector_type(8)));
typedef float  f32x4  __attribute__((ext_vector_type(4)));
typedef u16    u16x8  __attribute__((ext_vector_type(8)));
typedef u16    u16x4  __attribute__((ext_vector_type(4)));

__device__ __forceinline__ u16 f2bf(float f) {
    union { float f; unsigned u; } v; v.f = f;
    unsigned r = (v.u + 0x7FFFu + ((v.u >> 16) & 1u)) >> 16;
    return (u16)r;
}

// ---------------------------------------------------------------------------
// prep: blocks 0..63 convert x -> bf16; blocks 64..255 transpose [Wq|Wkv] ->
// Wt[1536][512] bf16; blocks 256..319 transpose Wo -> Wot[512][512] bf16.
// ---------------------------------------------------------------------------
__global__ __launch_bounds__(256) void prep(const float* __restrict__ x,
                                            const float* __restrict__ Wq,
                                            const float* __restrict__ Wkv,
                                            const float* __restrict__ Wo,
                                            u16* __restrict__ xb,
                                            u16* __restrict__ Wt,
                                            u16* __restrict__ Wot) {
    __shared__ float tile[64][65];
    int bx = blockIdx.x, tid = threadIdx.x;
    if (bx < 64) {
        int base4 = bx * 4096;               // float4 index
#pragma unroll
        for (int u = 0; u < 16; ++u) {
            int i4 = base4 + u * 256 + tid;
            float4 v = ((const float4*)x)[i4];
            u16x4 o = { f2bf(v.x), f2bf(v.y), f2bf(v.z), f2bf(v.w) };
            *(u16x4*)&xb[i4 * 4] = o;
        }
        return;
    }
    int tt = bx - 64;
    bool isQKV = (tt < 192);
    int tc, tr;
    if (isQKV) { tc = tt % 24; tr = tt / 24; }
    else       { tt -= 192; tc = tt & 7; tr = tt >> 3; }

    int rr = tid >> 4, c4 = (tid & 15) * 4;
#pragma unroll
    for (int u = 0; u < 4; ++u) {
        int row = u * 16 + rr;
        int k = tr * 64 + row;
        int c = tc * 64 + c4;
        float4 v;
        if (isQKV) v = (c < 512) ? *(const float4*)&Wq[k * 512 + c]
                                 : *(const float4*)&Wkv[k * 1024 + (c - 512)];
        else       v = *(const float4*)&Wo[k * 512 + c];
        tile[row][c4 + 0] = v.x; tile[row][c4 + 1] = v.y;
        tile[row][c4 + 2] = v.z; tile[row][c4 + 3] = v.w;
    }
    __syncthreads();
#pragma unroll
    for (int u = 0; u < 4; ++u) {
        int trow = u * 16 + rr;              // output col index within tile
        u16x4 o;
#pragma unroll
        for (int i = 0; i < 4; ++i) o[i] = f2bf(tile[c4 + i][trow]);
        int t_glob = tc * 64 + trow;
        int k_glob = tr * 64 + c4;
        if (isQKV) *(u16x4*)&Wt[t_glob * 512 + k_glob] = o;
        else       *(u16x4*)&Wot[t_glob * 512 + k_glob] = o;
    }
}

// ---------------------------------------------------------------------------
// Gates: sigmoid(x @ Wg) -> gates[h][n]   (f32, tiny)
// ---------------------------------------------------------------------------
__global__ __launch_bounds__(256) void gates_kernel(const float* __restrict__ x,
                                                    const float* __restrict__ Wg,
                                                    float* __restrict__ gates) {
    int t = blockIdx.x * 256 + threadIdx.x;
    int n = t >> 3, h = t & 7;
    float acc = 0.f;
    for (int k = 0; k < DMODEL; k += 4) {
        float4 xv = *(const float4*)&x[n * DMODEL + k];
        acc += xv.x * Wg[(k + 0) * NH + h] + xv.y * Wg[(k + 1) * NH + h]
             + xv.z * Wg[(k + 2) * NH + h] + xv.w * Wg[(k + 3) * NH + h];
    }
    gates[h * NQ + n] = 1.f / (1.f + expf(-acc));
}

// ---------------------------------------------------------------------------
// RoPE on cached K rows 0..511 -> k_bf. pos = row.
// ---------------------------------------------------------------------------
__global__ __launch_bounds__(256) void cache_k_rope(const float* __restrict__ cache_k,
                                                    u16* __restrict__ kb) {
    int h = blockIdx.y, r0 = blockIdx.x * 64;
    int tid = threadIdx.x;
#pragma unroll
    for (int u = 0; u < 8; ++u) {
        int idx = u * 256 + tid;
        int row = idx >> 5, j = idx & 31;
        int r = r0 + row;
        float a = cache_k[(h * MEMT + r) * DHD + j];
        float b = cache_k[(h * MEMT + r) * DHD + 32 + j];
        float invf = powf(10000.f, -(float)j * (1.f / 32.f));
        float ss, sc;
        sincosf((float)r * invf, &ss, &sc);
        kb[(h * KVT + r) * DHD + j]      = f2bf(a * sc - b * ss);
        kb[(h * KVT + r) * DHD + 32 + j] = f2bf(b * sc + a * ss);
    }
}

// ---------------------------------------------------------------------------
// V transpose: bx<8 from cache_v (f32), else from vn_bf (bf16) -> vT[h][d][kv]
// ---------------------------------------------------------------------------
__global__ __launch_bounds__(256) void v_transpose(const float* __restrict__ cache_v,
                                                   const u16* __restrict__ vn,
                                                   u16* __restrict__ vt) {
    __shared__ u16 tile[64][66];
    int h = blockIdx.y, bx = blockIdx.x;
    int tid = threadIdx.x;
    int rr = tid >> 4, c4 = (tid & 15) * 4;
    if (bx < 8) {
        int r0 = bx * 64;
#pragma unroll
        for (int u = 0; u < 4; ++u) {
            int row = u * 16 + rr;
            float4 v = *(const float4*)&cache_v[(h * MEMT + r0 + row) * DHD + c4];
            tile[row][c4 + 0] = f2bf(v.x); tile[row][c4 + 1] = f2bf(v.y);
            tile[row][c4 + 2] = f2bf(v.z); tile[row][c4 + 3] = f2bf(v.w);
        }
    } else {
        int n0 = (bx - 8) * 64;
#pragma unroll
        for (int u = 0; u < 4; ++u) {
            int row = u * 16 + rr;
            u16x4 v = *(const u16x4*)&vn[(h * NQ + n0 + row) * DHD + c4];
            tile[row][c4 + 0] = v[0]; tile[row][c4 + 1] = v[1];
            tile[row][c4 + 2] = v[2]; tile[row][c4 + 3] = v[3];
        }
    }
    __syncthreads();
    int kvbase = bx * 64;                    // cache rows land at bx*64, new at 512+(bx-8)*64 == bx*64
#pragma unroll
    for (int u = 0; u < 4; ++u) {
        int d = u * 16 + rr;
        u16x4 o = { tile[c4 + 0][d], tile[c4 + 1][d], tile[c4 + 2][d], tile[c4 + 3][d] };
        *(u16x4*)&vt[(h * DHD + d) * KVT + kvbase + c4] = o;
    }
}

// ---------------------------------------------------------------------------
// bf16 MFMA GEMM: C[2048, Ncols] = A[2048,512] @ Bt[Ncols,512]^T.
// Block: 4 waves, tile 64(M) x 64(N). Wave: rows (w>>1)*32..+32, col pair
// {hc+lr, hc+32+lr}, hc = (w&1)*16. MODE 0: qkv epilogue (RoPE q/k, split
// heads); MODE 1: plain f32 store.
// ---------------------------------------------------------------------------
template<int MODE>
__global__ __launch_bounds__(256) void gemm_mfma(const u16* __restrict__ A,
                                                 const u16* __restrict__ Bt,
                                                 u16* __restrict__ o_q,
                                                 u16* __restrict__ o_k,
                                                 u16* __restrict__ o_v,
                                                 float* __restrict__ o_f) {
    int bx = blockIdx.x, by = blockIdx.y;
    int tid = threadIdx.x;
    int w = tid >> 6, lane = tid & 63;
    int lr = lane & 15, lg = lane >> 4;
    int rowbase = by * 64 + (w >> 1) * 32;
    int colbase = bx * 64 + (w & 1) * 16;

    f32x4 acc[2][2];
#pragma unroll
    for (int i = 0; i < 2; ++i)
#pragma unroll
        for (int j = 0; j < 2; ++j) { f32x4 z = {0.f, 0.f, 0.f, 0.f}; acc[i][j] = z; }

    const u16* a0 = A + (rowbase + lr) * 512 + lg * 8;
    const u16* a1 = a0 + 16 * 512;
    const u16* b0 = Bt + (colbase + lr) * 512 + lg * 8;
    const u16* b1 = b0 + 32 * 512;

#pragma unroll 4
    for (int k0 = 0; k0 < 512; k0 += 32) {
        bf16x8 fa0 = __builtin_bit_cast(bf16x8, *(const u16x8*)(a0 + k0));
        bf16x8 fa1 = __builtin_bit_cast(bf16x8, *(const u16x8*)(a1 + k0));
        bf16x8 fb0 = __builtin_bit_cast(bf16x8, *(const u16x8*)(b0 + k0));
        bf16x8 fb1 = __builtin_bit_cast(bf16x8, *(const u16x8*)(b1 + k0));
        acc[0][0] = __builtin_amdgcn_mfma_f32_16x16x32_bf16(fa0, fb0, acc[0][0], 0, 0, 0);
        acc[0][1] = __builtin_amdgcn_mfma_f32_16x16x32_bf16(fa0, fb1, acc[0][1], 0, 0, 0);
        acc[1][0] = __builtin_amdgcn_mfma_f32_16x16x32_bf16(fa1, fb0, acc[1][0], 0, 0, 0);
        acc[1][1] = __builtin_amdgcn_mfma_f32_16x16x32_bf16(fa1, fb1, acc[1][1], 0, 0, 0);
    }

    if (MODE == 1) {
#pragma unroll
        for (int rt = 0; rt < 2; ++rt)
#pragma unroll
            for (int r = 0; r < 4; ++r) {
                int n = rowbase + rt * 16 + lg * 4 + r;
                o_f[n * DMODEL + colbase + lr]      = acc[rt][0][r];
                o_f[n * DMODEL + colbase + 32 + lr] = acc[rt][1][r];
            }
        return;
    }

    // MODE 0: qkv epilogue. col = bx*64 + d, d pair (j, j+32), j = hc+lr.
    int j = (colbase & 63) + lr;             // 0..31
    int region = bx >> 3;                    // 0=q, 1=k, 2=v
    int h = bx & 7;
    float invf = powf(10000.f, -(float)j * (1.f / 32.f));
#pragma unroll
    for (int rt = 0; rt < 2; ++rt)
#pragma unroll
        for (int r = 0; r < 4; ++r) {
            int n = rowbase + rt * 16 + lg * 4 + r;
            float a = acc[rt][0][r], b = acc[rt][1][r];
            if (region == 2) {
                o_v[(h * NQ + n) * DHD + j]      = f2bf(a);
                o_v[(h * NQ + n) * DHD + 32 + j] = f2bf(b);
            } else {
                float ss, sc;
                sincosf((float)(512 + n) * invf, &ss, &sc);
                u16 e0 = f2bf(a * sc - b * ss);
                u16 e1 = f2bf(b * sc + a * ss);
                if (region == 0) {
                    o_q[(h * NQ + n) * DHD + j]      = e0;
                    o_q[(h * NQ + n) * DHD + 32 + j] = e1;
                } else {
                    o_k[(h * KVT + 512 + n) * DHD + j]      = e0;
                    o_k[(h * KVT + 512 + n) * DHD + 32 + j] = e1;
                }
            }
        }
}

// ---------------------------------------------------------------------------
// MFMA flash attention (unchanged from round 2 except bf16 output).
// ---------------------------------------------------------------------------
#define LOADK(BK, BEP, C0)                                                     \
  _Pragma("unroll")                                                            \
  for (int t = 0; t < 4; ++t) {                                                \
    const u16* kr = kb + ((h * KVT + (C0) + t * 16 + lr) * DHD + lg * 8);      \
    BK[t][0] = __builtin_bit_cast(bf16x8, *(const u16x8*)kr);                  \
    BK[t][1] = __builtin_bit_cast(bf16x8, *(const u16x8*)(kr + 32));           \
    BEP[t] = ep[(C0) + t * 16 + lr];                                           \
  }

#define DO_CHUNK(C0, BK, BEP, PREF, NBK, NBEP)                                 \
  {                                                                            \
    bf16x8 bV[4][2];                                                           \
    _Pragma("unroll")                                                          \
    for (int t = 0; t < 4; ++t) {                                              \
      const u16* vr = vtb + ((h * DHD + t * 16 + lr) * KVT + (C0) + lg * 8);   \
      bV[t][0] = __builtin_bit_cast(bf16x8, *(const u16x8*)vr);                \
      bV[t][1] = __builtin_bit_cast(bf16x8, *(const u16x8*)(vr + 32));         \
    }                                                                          \
    f32x4 s[4];                                                                \
    _Pragma("unroll")                                                          \
    for (int t = 0; t < 4; ++t) {                                              \
      f32x4 z = {0.f, 0.f, 0.f, 0.f};                                          \
      s[t] = __builtin_amdgcn_mfma_f32_16x16x32_bf16(aQ[0], BK[t][0], z, 0, 0, 0); \
      s[t] = __builtin_amdgcn_mfma_f32_16x16x32_bf16(aQ[1], BK[t][1], s[t], 0, 0, 0); \
    }                                                                          \
    if (PREF) { LOADK(NBK, NBEP, (C0) + 64) }                                  \
    float rmax[4] = {NEGF, NEGF, NEGF, NEGF};                                  \
    _Pragma("unroll")                                                          \
    for (int t = 0; t < 4; ++t) {                                              \
      int key = (C0) + t * 16 + lr;                                            \
      int ek = BEP[t];                                                         \
      _Pragma("unroll")                                                        \
      for (int r = 0; r < 4; ++r) {                                            \
        bool vld = (key <= qpos[r]) && (ek == epq[r]);                         \
        float sv = vld ? s[t][r] * QSCALE : NEGF;                              \
        s[t][r] = sv;                                                          \
        rmax[r] = fmaxf(rmax[r], sv);                                          \
      }                                                                        \
    }                                                                          \
    _Pragma("unroll")                                                          \
    for (int mm = 1; mm < 16; mm <<= 1) {                                      \
      _Pragma("unroll")                                                        \
      for (int r = 0; r < 4; ++r)                                              \
        rmax[r] = fmaxf(rmax[r], __shfl_xor(rmax[r], mm, 64));                 \
    }                                                                          \
    float alpha[4];                                                            \
    _Pragma("unroll")                                                          \
    for (int r = 0; r < 4; ++r) {                                              \
      float mn = fmaxf(mrun[r], rmax[r]);                                      \
      alpha[r] = __expf(mrun[r] - mn);                                         \
      mrun[r] = mn;                                                            \
      lsum[r] *= alpha[r];                                                     \
    }                                                                          \
    _Pragma("unroll")                                                          \
    for (int t = 0; t < 4; ++t)                                                \
      _Pragma("unroll")                                                        \
      for (int r = 0; r < 4; ++r) o[t][r] *= alpha[r];                         \
    float psum[4] = {0.f, 0.f, 0.f, 0.f};                                      \
    _Pragma("unroll")                                                          \
    for (int t = 0; t < 4; ++t) {                                              \
      _Pragma("unroll")                                                        \
      for (int r = 0; r < 4; ++r) {                                            \
        float sv = s[t][r];                                                    \
        float p = (sv <= -1e29f) ? 0.f : __expf(sv - mrun[r]);                 \
        psum[r] += p;                                                          \
        int qq = lg * 4 + r;                                                   \
        int kk2 = t * 16 + lr;                                                 \
        pl[qq * 64 + (kk2 ^ ((qq & 7) << 3))] = f2bf(p);                       \
      }                                                                        \
    }                                                                          \
    _Pragma("unroll")                                                          \
    for (int mm = 1; mm < 16; mm <<= 1) {                                      \
      _Pragma("unroll")                                                        \
      for (int r = 0; r < 4; ++r) psum[r] += __shfl_xor(psum[r], mm, 64);      \
    }                                                                          \
    _Pragma("unroll")                                                          \
    for (int r = 0; r < 4; ++r) lsum[r] += psum[r];                            \
    bf16x8 aP[2];                                                              \
    {                                                                          \
      int sw = (lr & 7) << 3;                                                  \
      aP[0] = __builtin_bit_cast(bf16x8, *(const u16x8*)&pl[lr * 64 + ((lg * 8) ^ sw)]);        \
      aP[1] = __builtin_bit_cast(bf16x8, *(const u16x8*)&pl[lr * 64 + ((32 + lg * 8) ^ sw)]);   \
    }                                                                          \
    _Pragma("unroll")                                                          \
    for (int t = 0; t < 4; ++t) {                                              \
      o[t] = __builtin_amdgcn_mfma_f32_16x16x32_bf16(aP[0], bV[t][0], o[t], 0, 0, 0); \
      o[t] = __builtin_amdgcn_mfma_f32_16x16x32_bf16(aP[1], bV[t][1], o[t], 0, 0, 0); \
    }                                                                          \
  }

__global__ __launch_bounds__(256, 1) void attn_mfma(const u16* __restrict__ qb,
                                                    const u16* __restrict__ kb,
                                                    const u16* __restrict__ vtb,
                                                    const float* __restrict__ gates,
                                                    const int* __restrict__ ep,
                                                    u16* __restrict__ outp) {
    __shared__ u16 plds[4][16 * 64];
    int h = blockIdx.y;
    int q0 = blockIdx.x * 64;
    int tid = threadIdx.x;
    int w = tid >> 6, lane = tid & 63;
    int lr = lane & 15, lg = lane >> 4;
    int qbase = q0 + w * 16;
    u16* pl = plds[w];

    bf16x8 aQ[2];
    {
        const u16* qrow = qb + ((h * NQ + qbase + lr) * DHD + lg * 8);
        aQ[0] = __builtin_bit_cast(bf16x8, *(const u16x8*)qrow);
        aQ[1] = __builtin_bit_cast(bf16x8, *(const u16x8*)(qrow + 32));
    }

    int qpos[4], epq[4];
    float gq[4];
#pragma unroll
    for (int r = 0; r < 4; ++r) {
        int q = qbase + lg * 4 + r;
        qpos[r] = 512 + q;
        epq[r] = ep[512 + q];
        gq[r] = gates[h * NQ + q];
    }

    f32x4 o[4];
    float mrun[4], lsum[4];
#pragma unroll
    for (int t = 0; t < 4; ++t) { f32x4 z = {0.f,0.f,0.f,0.f}; o[t] = z; }
#pragma unroll
    for (int r = 0; r < 4; ++r) { mrun[r] = NEGF; lsum[r] = 0.f; }

    int c_lo = q0 & ~511;
    int nch = 9 + ((q0 >> 6) & 7);

    bf16x8 bKA[4][2], bKB[4][2];
    int epA[4], epB[4];

    LOADK(bKA, epA, c_lo)
    int c0 = c_lo, ci = 0;
    while (true) {
        bool more = (ci + 1 < nch);
        DO_CHUNK(c0, bKA, epA, more, bKB, epB)
        ++ci; c0 += 64;
        if (!more) break;
        bool more2 = (ci + 1 < nch);
        DO_CHUNK(c0, bKB, epB, more2, bKA, epA)
        ++ci; c0 += 64;
        if (!more2) break;
    }

#pragma unroll
    for (int r = 0; r < 4; ++r) {
        float inv = gq[r] / lsum[r];
        int q = qbase + lg * 4 + r;
#pragma unroll
        for (int t = 0; t < 4; ++t)
            outp[q * DMODEL + h * DHD + t * 16 + lr] = f2bf(o[t][r] * inv);
    }
}

// ---------------------------------------------------------------------------
extern "C" void kernel_launch(void* const* d_in, const int* in_sizes, int n_in,
                              void* d_out, int out_size, void* d_ws, size_t ws_size,
                              hipStream_t stream) {
    const float* x       = (const float*)d_in[0];
    const float* cache_k = (const float*)d_in[1];
    const float* cache_v = (const float*)d_in[2];
    const int*   ep      = (const int*)  d_in[3];
    const float* Wq      = (const float*)d_in[4];
    const float* Wkv     = (const float*)d_in[5];
    const float* Wg      = (const float*)d_in[6];
    const float* Wo      = (const float*)d_in[7];
    float* out = (float*)d_out;

    u16* u = (u16*)d_ws;
    u16* x_bf    = u;                        // 1048576
    u16* Wt      = x_bf + 1048576;           // 786432
    u16* Wot     = Wt + 786432;              // 262144
    u16* q_bf    = Wot + 262144;             // 1048576
    u16* k_bf    = q_bf + 1048576;           // 1310720
    u16* vn_bf   = k_bf + 1310720;           // 1048576
    u16* vT      = vn_bf + 1048576;          // 1310720
    u16* attn_bf = vT + 1310720;             // 1048576
    float* gatesw = (float*)(attn_bf + 1048576);   // 16384 f32  (~15.8 MB total)

    prep<<<320, 256, 0, stream>>>(x, Wq, Wkv, Wo, x_bf, Wt, Wot);
    gates_kernel<<<64, 256, 0, stream>>>(x, Wg, gatesw);
    cache_k_rope<<<dim3(8, 8), 256, 0, stream>>>(cache_k, k_bf);
    gemm_mfma<0><<<dim3(24, 32), 256, 0, stream>>>(x_bf, Wt, q_bf, k_bf, vn_bf, nullptr);
    v_transpose<<<dim3(40, 8), 256, 0, stream>>>(cache_v, vn_bf, vT);
    attn_mfma<<<dim3(32, 8), 256, 0, stream>>>(q_bf, k_bf, vT, gatesw, ep, attn_bf);
    gemm_mfma<1><<<dim3(8, 32), 256, 0, stream>>>(attn_bf, Wot, nullptr, nullptr, nullptr, out);
}

// Round 5
// 154.777 us; speedup vs baseline: 2.3588x; 1.0243x over previous
//
#include <hip/hip_runtime.h>
#include <math.h>

#define NQ     2048
#define DMODEL 512
#define NH     8
#define DHD    64
#define MEMT   512
#define KVT    2560
#define QSCALE 0.125f
#define NEGF   (-1e30f)

typedef unsigned short u16;
typedef __bf16 bf16x8 __attribute__((ext_vector_type(8)));
typedef float  f32x4  __attribute__((ext_vector_type(4)));
typedef u16    u16x8  __attribute__((ext_vector_type(8)));
typedef u16    u16x4  __attribute__((ext_vector_type(4)));

__device__ __forceinline__ u16 f2bf(float f) {
    union { float f; unsigned u; } v; v.f = f;
    unsigned r = (v.u + 0x7FFFu + ((v.u >> 16) & 1u)) >> 16;
    return (u16)r;
}

// ---------------------------------------------------------------------------
// prep: bx<64: x->bf16. bx 64..255: [Wq|Wkv] -> Wt[1536][512]. bx 256..319:
// Wo -> Wot[512][512]. bx 320..383: gates. bx 384..703: RoPE cos/sin table.
// ---------------------------------------------------------------------------
__global__ __launch_bounds__(256) void prep(const float* __restrict__ x,
                                            const float* __restrict__ Wq,
                                            const float* __restrict__ Wkv,
                                            const float* __restrict__ Wo,
                                            const float* __restrict__ Wg,
                                            u16* __restrict__ xb,
                                            u16* __restrict__ Wt,
                                            u16* __restrict__ Wot,
                                            float* __restrict__ gates,
                                            float2* __restrict__ cs) {
    __shared__ float tile[64][65];
    int bx = blockIdx.x, tid = threadIdx.x;

    if (bx >= 384) {                         // RoPE table: cs[pos*32+j]
        int t = (bx - 384) * 256 + tid;      // 0..81919
        int pos = t >> 5, j = t & 31;
        float invf = exp2f(-(float)j * (13.287712379549449f / 32.f));
        float ss, sc;
        sincosf((float)pos * invf, &ss, &sc);
        cs[t] = make_float2(sc, ss);
        return;
    }
    if (bx >= 320) {                         // gates = sigmoid(x @ Wg)
        int t = (bx - 320) * 256 + tid;
        int n = t >> 3, hh = t & 7;
        float acc = 0.f;
        for (int k = 0; k < DMODEL; k += 4) {
            float4 xv = *(const float4*)&x[n * DMODEL + k];
            acc += xv.x * Wg[(k + 0) * NH + hh] + xv.y * Wg[(k + 1) * NH + hh]
                 + xv.z * Wg[(k + 2) * NH + hh] + xv.w * Wg[(k + 3) * NH + hh];
        }
        gates[hh * NQ + n] = 1.f / (1.f + __expf(-acc));
        return;
    }
    if (bx < 64) {                           // x -> bf16
        int base4 = bx * 4096;
#pragma unroll
        for (int u = 0; u < 16; ++u) {
            int i4 = base4 + u * 256 + tid;
            float4 v = ((const float4*)x)[i4];
            u16x4 o = { f2bf(v.x), f2bf(v.y), f2bf(v.z), f2bf(v.w) };
            *(u16x4*)&xb[i4 * 4] = o;
        }
        return;
    }
    int tt = bx - 64;
    bool isQKV = (tt < 192);
    int tc, tr;
    if (isQKV) { tc = tt % 24; tr = tt / 24; }
    else       { tt -= 192; tc = tt & 7; tr = tt >> 3; }

    int rr = tid >> 4, c4 = (tid & 15) * 4;
#pragma unroll
    for (int u = 0; u < 4; ++u) {
        int row = u * 16 + rr;
        int k = tr * 64 + row;
        int c = tc * 64 + c4;
        float4 v;
        if (isQKV) v = (c < 512) ? *(const float4*)&Wq[k * 512 + c]
                                 : *(const float4*)&Wkv[k * 1024 + (c - 512)];
        else       v = *(const float4*)&Wo[k * 512 + c];
        tile[row][c4 + 0] = v.x; tile[row][c4 + 1] = v.y;
        tile[row][c4 + 2] = v.z; tile[row][c4 + 3] = v.w;
    }
    __syncthreads();
#pragma unroll
    for (int u = 0; u < 4; ++u) {
        int trow = u * 16 + rr;
        u16x4 o;
#pragma unroll
        for (int i = 0; i < 4; ++i) o[i] = f2bf(tile[c4 + i][trow]);
        int t_glob = tc * 64 + trow;
        int k_glob = tr * 64 + c4;
        if (isQKV) *(u16x4*)&Wt[t_glob * 512 + k_glob] = o;
        else       *(u16x4*)&Wot[t_glob * 512 + k_glob] = o;
    }
}

// ---------------------------------------------------------------------------
// kv_prep: bx<8: RoPE cached K rows (table lookup). bx 8..47: V transpose.
// ---------------------------------------------------------------------------
__global__ __launch_bounds__(256) void kv_prep(const float* __restrict__ cache_k,
                                               const float* __restrict__ cache_v,
                                               const u16* __restrict__ vn,
                                               const float2* __restrict__ cs,
                                               u16* __restrict__ kb,
                                               u16* __restrict__ vt) {
    __shared__ u16 tile[64][66];
    int h = blockIdx.y, bx = blockIdx.x;
    int tid = threadIdx.x;

    if (bx < 8) {                            // cache-K RoPE
        int r0 = bx * 64;
#pragma unroll
        for (int u = 0; u < 8; ++u) {
            int idx = u * 256 + tid;
            int row = idx >> 5, j = idx & 31;
            int r = r0 + row;
            float a = cache_k[(h * MEMT + r) * DHD + j];
            float b = cache_k[(h * MEMT + r) * DHD + 32 + j];
            float2 csv = cs[r * 32 + j];
            kb[(h * KVT + r) * DHD + j]      = f2bf(a * csv.x - b * csv.y);
            kb[(h * KVT + r) * DHD + 32 + j] = f2bf(b * csv.x + a * csv.y);
        }
        return;
    }

    int tb = bx - 8;
    int rr = tid >> 4, c4 = (tid & 15) * 4;
    if (tb < 8) {
        int r0 = tb * 64;
#pragma unroll
        for (int u = 0; u < 4; ++u) {
            int row = u * 16 + rr;
            float4 v = *(const float4*)&cache_v[(h * MEMT + r0 + row) * DHD + c4];
            tile[row][c4 + 0] = f2bf(v.x); tile[row][c4 + 1] = f2bf(v.y);
            tile[row][c4 + 2] = f2bf(v.z); tile[row][c4 + 3] = f2bf(v.w);
        }
    } else {
        int n0 = (tb - 8) * 64;
#pragma unroll
        for (int u = 0; u < 4; ++u) {
            int row = u * 16 + rr;
            u16x4 v = *(const u16x4*)&vn[(h * NQ + n0 + row) * DHD + c4];
            tile[row][c4 + 0] = v[0]; tile[row][c4 + 1] = v[1];
            tile[row][c4 + 2] = v[2]; tile[row][c4 + 3] = v[3];
        }
    }
    __syncthreads();
    int kvbase = tb * 64;                    // cache rows at tb*64, new at 512+(tb-8)*64
#pragma unroll
    for (int u = 0; u < 4; ++u) {
        int d = u * 16 + rr;
        u16x4 o = { tile[c4 + 0][d], tile[c4 + 1][d], tile[c4 + 2][d], tile[c4 + 3][d] };
        *(u16x4*)&vt[(h * DHD + d) * KVT + kvbase + c4] = o;
    }
}

// ---------------------------------------------------------------------------
// bf16 MFMA GEMM. MODE 0: qkv epilogue (table RoPE); MODE 1: f32 store.
// ---------------------------------------------------------------------------
template<int MODE>
__global__ __launch_bounds__(256) void gemm_mfma(const u16* __restrict__ A,
                                                 const u16* __restrict__ Bt,
                                                 const float2* __restrict__ cs,
                                                 u16* __restrict__ o_q,
                                                 u16* __restrict__ o_k,
                                                 u16* __restrict__ o_v,
                                                 float* __restrict__ o_f) {
    int bx = blockIdx.x, by = blockIdx.y;
    int tid = threadIdx.x;
    int w = tid >> 6, lane = tid & 63;
    int lr = lane & 15, lg = lane >> 4;
    int rowbase = by * 64 + (w >> 1) * 32;
    int colbase = bx * 64 + (w & 1) * 16;

    f32x4 acc[2][2];
#pragma unroll
    for (int i = 0; i < 2; ++i)
#pragma unroll
        for (int j = 0; j < 2; ++j) { f32x4 z = {0.f, 0.f, 0.f, 0.f}; acc[i][j] = z; }

    const u16* a0 = A + (rowbase + lr) * 512 + lg * 8;
    const u16* a1 = a0 + 16 * 512;
    const u16* b0 = Bt + (colbase + lr) * 512 + lg * 8;
    const u16* b1 = b0 + 32 * 512;

#pragma unroll 4
    for (int k0 = 0; k0 < 512; k0 += 32) {
        bf16x8 fa0 = __builtin_bit_cast(bf16x8, *(const u16x8*)(a0 + k0));
        bf16x8 fa1 = __builtin_bit_cast(bf16x8, *(const u16x8*)(a1 + k0));
        bf16x8 fb0 = __builtin_bit_cast(bf16x8, *(const u16x8*)(b0 + k0));
        bf16x8 fb1 = __builtin_bit_cast(bf16x8, *(const u16x8*)(b1 + k0));
        acc[0][0] = __builtin_amdgcn_mfma_f32_16x16x32_bf16(fa0, fb0, acc[0][0], 0, 0, 0);
        acc[0][1] = __builtin_amdgcn_mfma_f32_16x16x32_bf16(fa0, fb1, acc[0][1], 0, 0, 0);
        acc[1][0] = __builtin_amdgcn_mfma_f32_16x16x32_bf16(fa1, fb0, acc[1][0], 0, 0, 0);
        acc[1][1] = __builtin_amdgcn_mfma_f32_16x16x32_bf16(fa1, fb1, acc[1][1], 0, 0, 0);
    }

    if (MODE == 1) {
#pragma unroll
        for (int rt = 0; rt < 2; ++rt)
#pragma unroll
            for (int r = 0; r < 4; ++r) {
                int n = rowbase + rt * 16 + lg * 4 + r;
                o_f[n * DMODEL + colbase + lr]      = acc[rt][0][r];
                o_f[n * DMODEL + colbase + 32 + lr] = acc[rt][1][r];
            }
        return;
    }

    int j = (colbase & 63) + lr;             // 0..31
    int region = bx >> 3;                    // 0=q, 1=k, 2=v
    int h = bx & 7;
#pragma unroll
    for (int rt = 0; rt < 2; ++rt)
#pragma unroll
        for (int r = 0; r < 4; ++r) {
            int n = rowbase + rt * 16 + lg * 4 + r;
            float a = acc[rt][0][r], b = acc[rt][1][r];
            if (region == 2) {
                o_v[(h * NQ + n) * DHD + j]      = f2bf(a);
                o_v[(h * NQ + n) * DHD + 32 + j] = f2bf(b);
            } else {
                float2 csv = cs[(512 + n) * 32 + j];
                u16 e0 = f2bf(a * csv.x - b * csv.y);
                u16 e1 = f2bf(b * csv.x + a * csv.y);
                if (region == 0) {
                    o_q[(h * NQ + n) * DHD + j]      = e0;
                    o_q[(h * NQ + n) * DHD + 32 + j] = e1;
                } else {
                    o_k[(h * KVT + 512 + n) * DHD + j]      = e0;
                    o_k[(h * KVT + 512 + n) * DHD + 32 + j] = e1;
                }
            }
        }
}

// ---------------------------------------------------------------------------
// Split-KV MFMA flash attention. Block = (32 queries, head): 4 waves =
// 2 q-subtiles x 2 kv-halves; (m,l,o) partials merged via LDS.
// ---------------------------------------------------------------------------
#define LOADK(BK, BEP, C0)                                                     \
  _Pragma("unroll")                                                            \
  for (int t = 0; t < 4; ++t) {                                                \
    const u16* kr = kb + ((h * KVT + (C0) + t * 16 + lr) * DHD + lg * 8);      \
    BK[t][0] = __builtin_bit_cast(bf16x8, *(const u16x8*)kr);                  \
    BK[t][1] = __builtin_bit_cast(bf16x8, *(const u16x8*)(kr + 32));           \
    BEP[t] = ep[(C0) + t * 16 + lr];                                           \
  }

#define DO_CHUNK(C0, BK, BEP, PREF, NBK, NBEP)                                 \
  {                                                                            \
    bf16x8 bV[4][2];                                                           \
    _Pragma("unroll")                                                          \
    for (int t = 0; t < 4; ++t) {                                              \
      const u16* vr = vtb + ((h * DHD + t * 16 + lr) * KVT + (C0) + lg * 8);   \
      bV[t][0] = __builtin_bit_cast(bf16x8, *(const u16x8*)vr);                \
      bV[t][1] = __builtin_bit_cast(bf16x8, *(const u16x8*)(vr + 32));         \
    }                                                                          \
    f32x4 s[4];                                                                \
    _Pragma("unroll")                                                          \
    for (int t = 0; t < 4; ++t) {                                              \
      f32x4 z = {0.f, 0.f, 0.f, 0.f};                                          \
      s[t] = __builtin_amdgcn_mfma_f32_16x16x32_bf16(aQ[0], BK[t][0], z, 0, 0, 0); \
      s[t] = __builtin_amdgcn_mfma_f32_16x16x32_bf16(aQ[1], BK[t][1], s[t], 0, 0, 0); \
    }                                                                          \
    if (PREF) { LOADK(NBK, NBEP, (C0) + 64) }                                  \
    float rmax[4] = {NEGF, NEGF, NEGF, NEGF};                                  \
    _Pragma("unroll")                                                          \
    for (int t = 0; t < 4; ++t) {                                              \
      int key = (C0) + t * 16 + lr;                                            \
      int ek = BEP[t];                                                         \
      _Pragma("unroll")                                                        \
      for (int r = 0; r < 4; ++r) {                                            \
        bool vld = (key <= qpos[r]) && (ek == epq[r]);                         \
        float sv = vld ? s[t][r] * QSCALE : NEGF;                              \
        s[t][r] = sv;                                                          \
        rmax[r] = fmaxf(rmax[r], sv);                                          \
      }                                                                        \
    }                                                                          \
    _Pragma("unroll")                                                          \
    for (int mm = 1; mm < 16; mm <<= 1) {                                      \
      _Pragma("unroll")                                                        \
      for (int r = 0; r < 4; ++r)                                              \
        rmax[r] = fmaxf(rmax[r], __shfl_xor(rmax[r], mm, 64));                 \
    }                                                                          \
    float alpha[4];                                                            \
    _Pragma("unroll")                                                          \
    for (int r = 0; r < 4; ++r) {                                              \
      float mn = fmaxf(mrun[r], rmax[r]);                                      \
      alpha[r] = __expf(mrun[r] - mn);                                         \
      mrun[r] = mn;                                                            \
      lsum[r] *= alpha[r];                                                     \
    }                                                                          \
    _Pragma("unroll")                                                          \
    for (int t = 0; t < 4; ++t)                                                \
      _Pragma("unroll")                                                        \
      for (int r = 0; r < 4; ++r) o[t][r] *= alpha[r];                         \
    float psum[4] = {0.f, 0.f, 0.f, 0.f};                                      \
    _Pragma("unroll")                                                          \
    for (int t = 0; t < 4; ++t) {                                              \
      _Pragma("unroll")                                                        \
      for (int r = 0; r < 4; ++r) {                                            \
        float sv = s[t][r];                                                    \
        float p = (sv <= -1e29f) ? 0.f : __expf(sv - mrun[r]);                 \
        psum[r] += p;                                                          \
        int qq = lg * 4 + r;                                                   \
        int kk2 = t * 16 + lr;                                                 \
        pl[qq * 64 + (kk2 ^ ((qq & 7) << 3))] = f2bf(p);                       \
      }                                                                        \
    }                                                                          \
    _Pragma("unroll")                                                          \
    for (int mm = 1; mm < 16; mm <<= 1) {                                      \
      _Pragma("unroll")                                                        \
      for (int r = 0; r < 4; ++r) psum[r] += __shfl_xor(psum[r], mm, 64);      \
    }                                                                          \
    _Pragma("unroll")                                                          \
    for (int r = 0; r < 4; ++r) lsum[r] += psum[r];                            \
    bf16x8 aP[2];                                                              \
    {                                                                          \
      int sw = (lr & 7) << 3;                                                  \
      aP[0] = __builtin_bit_cast(bf16x8, *(const u16x8*)&pl[lr * 64 + ((lg * 8) ^ sw)]);        \
      aP[1] = __builtin_bit_cast(bf16x8, *(const u16x8*)&pl[lr * 64 + ((32 + lg * 8) ^ sw)]);   \
    }                                                                          \
    _Pragma("unroll")                                                          \
    for (int t = 0; t < 4; ++t) {                                              \
      o[t] = __builtin_amdgcn_mfma_f32_16x16x32_bf16(aP[0], bV[t][0], o[t], 0, 0, 0); \
      o[t] = __builtin_amdgcn_mfma_f32_16x16x32_bf16(aP[1], bV[t][1], o[t], 0, 0, 0); \
    }                                                                          \
  }

__global__ __launch_bounds__(256, 2) void attn_mfma(const u16* __restrict__ qb,
                                                    const u16* __restrict__ kb,
                                                    const u16* __restrict__ vtb,
                                                    const float* __restrict__ gates,
                                                    const int* __restrict__ ep,
                                                    u16* __restrict__ outp) {
    __shared__ u16 plds[4][16 * 64];
    __shared__ float o_l[2][16][68];
    __shared__ float ml_l[2][2][16];

    int h = blockIdx.y;
    int q0 = blockIdx.x * 32;
    int tid = threadIdx.x;
    int w = tid >> 6, lane = tid & 63;
    int lr = lane & 15, lg = lane >> 4;
    int qsub = w & 1, kvh = w >> 1;
    int qbase = q0 + qsub * 16;
    u16* pl = plds[w];

    bf16x8 aQ[2];
    {
        const u16* qrow = qb + ((h * NQ + qbase + lr) * DHD + lg * 8);
        aQ[0] = __builtin_bit_cast(bf16x8, *(const u16x8*)qrow);
        aQ[1] = __builtin_bit_cast(bf16x8, *(const u16x8*)(qrow + 32));
    }

    int qpos[4], epq[4];
    float gq[4];
#pragma unroll
    for (int r = 0; r < 4; ++r) {
        int q = qbase + lg * 4 + r;
        qpos[r] = 512 + q;
        epq[r] = ep[512 + q];
        gq[r] = gates[h * NQ + q];
    }

    f32x4 o[4];
    float mrun[4], lsum[4];
#pragma unroll
    for (int t = 0; t < 4; ++t) { f32x4 z = {0.f,0.f,0.f,0.f}; o[t] = z; }
#pragma unroll
    for (int r = 0; r < 4; ++r) { mrun[r] = NEGF; lsum[r] = 0.f; }

    int c_lo = q0 & ~511;
    int nch = (544 + (q0 & 511) + 63) >> 6;
    int n0 = nch >> 1;
    int my_n = kvh ? (nch - n0) : n0;
    int c0 = c_lo + (kvh ? (n0 << 6) : 0);

    bf16x8 bKA[4][2], bKB[4][2];
    int epA[4], epB[4];

    LOADK(bKA, epA, c0)
    int ci = 0;
    while (true) {
        bool more = (ci + 1 < my_n);
        DO_CHUNK(c0, bKA, epA, more, bKB, epB)
        ++ci; c0 += 64;
        if (!more) break;
        bool more2 = (ci + 1 < my_n);
        DO_CHUNK(c0, bKB, epB, more2, bKA, epA)
        ++ci; c0 += 64;
        if (!more2) break;
    }

    if (kvh == 1) {
#pragma unroll
        for (int r = 0; r < 4; ++r) {
            ml_l[qsub][0][lg * 4 + r] = mrun[r];
            ml_l[qsub][1][lg * 4 + r] = lsum[r];
        }
#pragma unroll
        for (int t = 0; t < 4; ++t)
#pragma unroll
            for (int r = 0; r < 4; ++r)
                o_l[qsub][lg * 4 + r][t * 16 + lr] = o[t][r];
    }
    __syncthreads();
    if (kvh == 0) {
#pragma unroll
        for (int r = 0; r < 4; ++r) {
            int row = lg * 4 + r;
            float m1 = ml_l[qsub][0][row], l1 = ml_l[qsub][1][row];
            float m0 = mrun[r], l0 = lsum[r];
            float mm2 = fmaxf(m0, m1);
            float f0 = (m0 <= -1e29f) ? 0.f : __expf(m0 - mm2);
            float f1 = (m1 <= -1e29f) ? 0.f : __expf(m1 - mm2);
            float lt = l0 * f0 + l1 * f1;
            float inv = gq[r] / lt;
            int q = qbase + row;
#pragma unroll
            for (int t = 0; t < 4; ++t) {
                float o1 = o_l[qsub][row][t * 16 + lr];
                outp[q * DMODEL + h * DHD + t * 16 + lr] =
                    f2bf((o[t][r] * f0 + o1 * f1) * inv);
            }
        }
    }
}

// ---------------------------------------------------------------------------
extern "C" void kernel_launch(void* const* d_in, const int* in_sizes, int n_in,
                              void* d_out, int out_size, void* d_ws, size_t ws_size,
                              hipStream_t stream) {
    const float* x       = (const float*)d_in[0];
    const float* cache_k = (const float*)d_in[1];
    const float* cache_v = (const float*)d_in[2];
    const int*   ep      = (const int*)  d_in[3];
    const float* Wq      = (const float*)d_in[4];
    const float* Wkv     = (const float*)d_in[5];
    const float* Wg      = (const float*)d_in[6];
    const float* Wo      = (const float*)d_in[7];
    float* out = (float*)d_out;

    u16* u = (u16*)d_ws;
    u16* x_bf    = u;                        // 1048576
    u16* Wt      = x_bf + 1048576;           // 786432
    u16* Wot     = Wt + 786432;              // 262144
    u16* q_bf    = Wot + 262144;             // 1048576
    u16* k_bf    = q_bf + 1048576;           // 1310720
    u16* vn_bf   = k_bf + 1310720;           // 1048576
    u16* vT      = vn_bf + 1048576;          // 1310720
    u16* attn_bf = vT + 1310720;             // 1048576
    float*  gatesw = (float*)(attn_bf + 1048576);  // 16384 f32
    float2* cs     = (float2*)(gatesw + 16384);    // 81920 float2

    prep<<<704, 256, 0, stream>>>(x, Wq, Wkv, Wo, Wg, x_bf, Wt, Wot, gatesw, cs);
    gemm_mfma<0><<<dim3(24, 32), 256, 0, stream>>>(x_bf, Wt, cs, q_bf, k_bf, vn_bf, nullptr);
    kv_prep<<<dim3(48, 8), 256, 0, stream>>>(cache_k, cache_v, vn_bf, cs, k_bf, vT);
    attn_mfma<<<dim3(64, 8), 256, 0, stream>>>(q_bf, k_bf, vT, gatesw, ep, attn_bf);
    gemm_mfma<1><<<dim3(8, 32), 256, 0, stream>>>(attn_bf, Wot, nullptr, nullptr, nullptr, nullptr, out);
}